// Round 19
// baseline (60.414 us; speedup 1.0000x reference)
//
#include <hip/hip_runtime.h>
#include <hip/hip_bf16.h>

#define CIN  64
#define HH   128
#define WW   128
#define COUT 64
#define K2   9
#define HW   (HH * WW)

typedef __attribute__((ext_vector_type(8))) short bf16x8;
typedef __attribute__((ext_vector_type(4))) float f32x4;
typedef __attribute__((ext_vector_type(2))) float f32x2;

__device__ __forceinline__ unsigned short f2bf(float f) {
    __hip_bfloat16 h = __float2bfloat16(f);
    return *reinterpret_cast<unsigned short*>(&h);
}
// unpack dword holding 2 bf16 (lo=ch j, hi=ch j+1) -> f32x2
__device__ __forceinline__ f32x2 up2(unsigned int d) {
    f32x2 r;
    r[0] = __uint_as_float(d << 16);
    r[1] = __uint_as_float(d & 0xffff0000u);
    return r;
}
// async global->LDS, 16B per lane; lds dest = wave-uniform base + lane*16
__device__ __forceinline__ void gl2lds16(const unsigned short* g, unsigned short* l) {
    __builtin_amdgcn_global_load_lds(
        (const __attribute__((address_space(1))) unsigned int*)g,
        (__attribute__((address_space(3))) unsigned int*)l, 16, 0, 0);
}

// ---------------- prep: x fp32 NCHW -> bf16 slice-planes [b][s][y][x][8ch] ----------------
__launch_bounds__(256)
__global__ void xprep2_kernel(const float* __restrict__ x, unsigned short* __restrict__ xt) {
    const int idx = blockIdx.x * 256 + threadIdx.x;   // 2^20 total
    const int xw = idx & 127;
    const int y  = (idx >> 7) & 127;
    const int s  = (idx >> 14) & 7;
    const int b  = idx >> 17;
    const float* src = x + (((size_t)(b * CIN + s * 8) * HH) + y) * WW + xw;
    union { unsigned short us[8]; bf16x8 v; } u;
    #pragma unroll
    for (int j = 0; j < 8; ++j) u.us[j] = f2bf(src[(size_t)j * HW]);
    *(bf16x8*)(xt + ((((size_t)b * 8 + s) * HW) + y * WW + xw) * 8) = u.v;
}

// ---------------- prep: weight fp32 [o][c][k] -> bf16 MFMA-B-fragment order ----------------
// wtp[ ((k*2+ks)*4+nt)*512 + l*8 + j ] = W[o=nt*16+(l&15)][c=ks*32+(l>>4)*8+j][k]
__global__ void wprep_kernel(const float* __restrict__ w, unsigned short* __restrict__ wtp) {
    int idx = blockIdx.x * 256 + threadIdx.x;
    if (idx >= COUT * CIN * K2) return;
    int j  = idx & 7;
    int l  = (idx >> 3) & 63;
    int nt = (idx >> 9) & 3;
    int ks = (idx >> 11) & 1;
    int k  = idx >> 12;
    int o  = nt * 16 + (l & 15);
    int c  = ks * 32 + (l >> 4) * 8 + j;
    wtp[idx] = f2bf(w[(o * CIN + c) * K2 + k]);
}

// --- main: 16-wave blocks, taps 0-7 B in 64KB LDS (2-block residency), tap-8 B in regs ---
__launch_bounds__(1024, 2)
__global__ void dcn_kernel(const unsigned short* __restrict__ xt,
                           const float* __restrict__ off,
                           const unsigned short* __restrict__ wtp,
                           float* __restrict__ out) {
    extern __shared__ unsigned short lsB[];     // 65536 B: taps 0-7 of B (fragment order);
                                                // after tap loop, first 33.8 KB reused as sred
    const int tid = threadIdx.x;
    const int w   = tid >> 6;                   // wave 0..15
    const int l   = tid & 63;
    const int wr  = w & 7;                      // pixel row within tile (8 rows)
    const int wh  = w >> 3;                     // K half: channels wh*32 .. wh*32+31

    int bid = blockIdx.x;                       // 1024 blocks
    bid = (bid & 7) * 128 + (bid >> 3);         // XCD swizzle: one batch per XCD (bijective)
    const int b   = bid >> 7;
    const int t   = bid & 127;
    const int ty0 = (t >> 3) << 3;              // 16 y-tiles of 8
    const int tx0 = (t & 7) << 4;               // 8  x-tiles of 16

    const int g      = l >> 4;                  // k-slice quad within half
    const int lane16 = l & 15;                  // pixel x within row

    // -------- stage B taps 0-7 into LDS: 64 segments = 4 rounds x 16 waves (64 KB) --------
    #pragma unroll
    for (int r = 0; r < 4; ++r) {
        const int seg = r * 16 + w;
        gl2lds16(wtp + seg * 512 + l * 8, lsB + seg * 512);
    }

    // -------- tap-8 B fragments straight to registers (L2-hot; issued before barrier) -----
    bf16x8 bv8[4];
    #pragma unroll
    for (int nt = 0; nt < 4; ++nt)
        bv8[nt] = *(const bf16x8*)(wtp + (((8 * 2 + wh) * 4 + nt) * 64 + l) * 8);

    f32x4 acc[4] = {{0,0,0,0},{0,0,0,0},{0,0,0,0},{0,0,0,0}};

    const float* offb = off + (size_t)b * (2 * K2) * HW;
    // this wave's channel plane: channels (wh*4+g)*8 .. +8
    const unsigned short* xp = xt + ((size_t)b * 8 + (wh * 4 + g)) * HW * 8;

    // this lane's pixel
    const int ypA  = ty0 + wr;
    const int xpA  = tx0 + lane16;
    const int offp = ypA * WW + xpA;

    // ---- pipeline state: constant-indexed after full unroll (spill-safe, ~68 VGPR) ----
    f32x4 Pw[2];
    int   Pr0[2], Pr1[2];
    float oyv[2], oxv[2];
    bf16x8 Gst[2][4];                           // double-buffered gather stage (1 plane pair)
    bf16x8 bvv[4];
    bf16x8 af;

#define PARAMS(K, S) do {                                                     \
    const int kdy = (K) / 3 - 1, kdx = (K) % 3 - 1;                           \
    float py = oyv[S] + (float)(ypA + kdy);                                   \
    float px = oxv[S] + (float)(xpA + kdx);                                   \
    float fy = floorf(py), fx = floorf(px);                                   \
    float wy = py - fy, wxn = px - fx;                                        \
    int y0 = (int)fy, x0i = (int)fx;                                          \
    int yc0 = min(max(y0,     0), HH - 1);                                    \
    int yc1 = min(max(y0 + 1, 0), HH - 1);                                    \
    float ay0 = (y0 >= 0  && y0 <= HH - 1) ? (1.f - wy) : 0.f;                \
    float ay1 = (y0 >= -1 && y0 <= HH - 2) ? wy         : 0.f;                \
    int   xL  = min(max(x0i, 0), WW - 2);                                     \
    float bx0 = (x0i >= 0  && x0i <= WW - 1) ? (1.f - wxn) : 0.f;             \
    float bx1 = (x0i >= -1 && x0i <= WW - 2) ? wxn         : 0.f;             \
    bool  sw  = (x0i != xL);                                                  \
    float wxa = sw ? bx1 : bx0;                                               \
    float wxb = sw ? bx0 : bx1;                                               \
    Pw[S][0] = ay0 * wxa; Pw[S][1] = ay0 * wxb;                               \
    Pw[S][2] = ay1 * wxa; Pw[S][3] = ay1 * wxb;                               \
    Pr0[S] = (yc0 * WW + xL) * 8;                                             \
    Pr1[S] = (yc1 * WW + xL) * 8;                                             \
} while (0)

#define GATHER(S) do {                                                        \
    const unsigned short* r0p = xp + Pr0[S];                                  \
    const unsigned short* r1p = xp + Pr1[S];                                  \
    Gst[S][0] = *(const bf16x8*)(r0p); Gst[S][1] = *(const bf16x8*)(r0p + 8); \
    Gst[S][2] = *(const bf16x8*)(r1p); Gst[S][3] = *(const bf16x8*)(r1p + 8); \
} while (0)

#define INTERP(S) do {                                                        \
    union { bf16x8 v; unsigned int d[4]; } ua, ub, uc, ud;                    \
    ua.v = Gst[S][0]; ub.v = Gst[S][1]; uc.v = Gst[S][2]; ud.v = Gst[S][3];   \
    union { unsigned short us[8]; bf16x8 v; } rr;                             \
    _Pragma("unroll")                                                         \
    for (int q = 0; q < 4; ++q) {                                             \
        f32x2 v = up2(ua.d[q]) * Pw[S][0] + up2(ub.d[q]) * Pw[S][1]           \
                + up2(uc.d[q]) * Pw[S][2] + up2(ud.d[q]) * Pw[S][3];          \
        rr.us[2*q]   = f2bf(v[0]);                                            \
        rr.us[2*q+1] = f2bf(v[1]);                                            \
    }                                                                         \
    af = rr.v;                                                                \
} while (0)

#define BVLOAD(K) do {                                                        \
    _Pragma("unroll")                                                         \
    for (int nt = 0; nt < 4; ++nt)                                            \
        bvv[nt] = *(const bf16x8*)(&lsB[(((K) * 2 + wh) * 4 + nt) * 512 + l * 8]); \
} while (0)

#define DOMFMA() do {                                                         \
    __builtin_amdgcn_s_setprio(1);                                            \
    acc[0] = __builtin_amdgcn_mfma_f32_16x16x32_bf16(af, bvv[0], acc[0], 0, 0, 0); \
    acc[1] = __builtin_amdgcn_mfma_f32_16x16x32_bf16(af, bvv[1], acc[1], 0, 0, 0); \
    acc[2] = __builtin_amdgcn_mfma_f32_16x16x32_bf16(af, bvv[2], acc[2], 0, 0, 0); \
    acc[3] = __builtin_amdgcn_mfma_f32_16x16x32_bf16(af, bvv[3], acc[3], 0, 0, 0); \
    __builtin_amdgcn_s_setprio(0);                                            \
} while (0)

    // -------- prologue: offsets taps 0/1, params 0, gather tap 0 --------
    oyv[0] = offb[offp];          oxv[0] = offb[HW + offp];
    oyv[1] = offb[2 * HW + offp]; oxv[1] = offb[3 * HW + offp];
    PARAMS(0, 0);
    GATHER(0);
    __syncthreads();                            // the ONLY pre-merge barrier: B staged

    // -------- 9 tap-steps, fully unrolled, NO barriers (B read-only, gathers in regs) -----
    #pragma unroll
    for (int s = 0; s < K2; ++s) {
        const int cur = s & 1, nxt = cur ^ 1;
        if (s < 8) {
            PARAMS(s + 1, nxt);
            if (s < 7) {
                oyv[cur] = offb[(2 * (s + 2)    ) * HW + offp];
                oxv[cur] = offb[(2 * (s + 2) + 1) * HW + offp];
            }
            GATHER(nxt);                        // in flight across BVLOAD+INTERP+MFMA(s)
        }
        if (s < 8) {
            BVLOAD(s);
        } else {
            bvv[0] = bv8[0]; bvv[1] = bv8[1]; bvv[2] = bv8[2]; bvv[3] = bv8[3];
        }
        INTERP(cur);
        DOMFMA();
    }

#undef PARAMS
#undef GATHER
#undef INTERP
#undef BVLOAD
#undef DOMFMA

    // -------- merge K-halves + store (sred aliases lsB; B is dead now) --------
    float (*sred)[66] = (float (*)[66])lsB;     // 128 x 66 f32 = 33792 B <= 65536
    __syncthreads();                            // all BVLOADs done before alias write
    // C/D layout: col = l&15 (=o within nt), row = (l>>4)*4+j (= pixel x = g*4+j)
    const int rq = g * 4;
    if (wh == 0) {
        #pragma unroll
        for (int nt = 0; nt < 4; ++nt)
            #pragma unroll
            for (int j = 0; j < 4; ++j)
                sred[wr * 16 + rq + j][nt * 16 + lane16] = acc[nt][j];
    }
    __syncthreads();
    if (wh == 1) {
        #pragma unroll
        for (int nt = 0; nt < 4; ++nt) {
            f32x4 v;
            #pragma unroll
            for (int j = 0; j < 4; ++j)
                v[j] = sred[wr * 16 + rq + j][nt * 16 + lane16] + acc[nt][j];
            const int o  = nt * 16 + lane16;
            const int yy = ty0 + wr;
            const int xx = tx0 + rq;
            *(f32x4*)&out[(((size_t)b * COUT + o) * HH + yy) * WW + xx] = v;
        }
    }
}

// ---------------- fallback path (no xt room): R0 kernel ----------------
__global__ void wprep_fb(const float* __restrict__ w, unsigned short* __restrict__ wt) {
    int idx = blockIdx.x * 256 + threadIdx.x;
    if (idx >= COUT * CIN * K2) return;
    int o = idx / (CIN * K2);
    int r = idx % (CIN * K2);
    int k = r / CIN;
    int c = r % CIN;
    wt[idx] = f2bf(w[o * (CIN * K2) + c * K2 + k]);
}

__launch_bounds__(256)
__global__ void dcn_fb(const float* __restrict__ x, const float* __restrict__ off,
                       const unsigned short* __restrict__ wt, float* __restrict__ out) {
    __shared__ unsigned short s_s[64 * 66];
    const int tid = threadIdx.x;
    const int w = tid >> 6, l = tid & 63;
    const int bid = blockIdx.x;
    const int b = bid >> 8, t = bid & 255;
    const int ty0 = (t >> 4) << 3, tx0 = (t & 15) << 3;
    const int iy = l >> 3, ix = l & 7;
    const int ypix = ty0 + iy, xpix = tx0 + ix;
    f32x4 acc[4] = {{0,0,0,0},{0,0,0,0},{0,0,0,0},{0,0,0,0}};
    const int c0w = w * 16;
    for (int k = 0; k < K2; ++k) {
        float dy = off[(((b * (2*K2)) + 2*k    ) * HH + ypix) * WW + xpix];
        float dx = off[(((b * (2*K2)) + 2*k + 1) * HH + ypix) * WW + xpix];
        float py = dy + (float)(k / 3 + ypix - 1);
        float px = dx + (float)(k % 3 + xpix - 1);
        float fy = floorf(py), fx = floorf(px);
        float wy = py - fy, wx = px - fx;
        int y0 = (int)fy, x0 = (int)fx;
        int yc0 = min(max(y0, 0), HH-1), yc1 = min(max(y0+1, 0), HH-1);
        float ay0 = (y0 >= 0 && y0 <= HH-1) ? (1.f-wy) : 0.f;
        float ay1 = (y0 >= -1 && y0 <= HH-2) ? wy : 0.f;
        int xL = min(max(x0, 0), WW-2);
        float bx0 = (x0 >= 0 && x0 <= WW-1) ? (1.f-wx) : 0.f;
        float bx1 = (x0 >= -1 && x0 <= WW-2) ? wx : 0.f;
        bool sw = (x0 != xL);
        float wxa = sw ? bx1 : bx0, wxb = sw ? bx0 : bx1;
        float W0x = ay0*wxa, W0y = ay0*wxb, W1x = ay1*wxa, W1y = ay1*wxb;
        const float* r0 = x + ((b * CIN + c0w) * HH + yc0) * WW + xL;
        const float* r1 = x + ((b * CIN + c0w) * HH + yc1) * WW + xL;
        unsigned short* sd = &s_s[l * 66 + c0w];
        #pragma unroll
        for (int cc = 0; cc < 16; ++cc) {
            sd[cc] = f2bf(W0x*r0[0] + W0y*r0[1] + W1x*r1[0] + W1y*r1[1]);
            r0 += HH*WW; r1 += HH*WW;
        }
        __syncthreads();
        const int o_lane = l & 15, q = l >> 4;
        #pragma unroll
        for (int ks = 0; ks < 2; ++ks) {
            const int cb = ks*32 + q*8;
            const int row = w*16 + o_lane;
            const unsigned int* sp = (const unsigned int*)s_s;
            const int ib = row*33 + (cb >> 1);
            union { unsigned int u[4]; bf16x8 v; } af;
            af.u[0]=sp[ib]; af.u[1]=sp[ib+1]; af.u[2]=sp[ib+2]; af.u[3]=sp[ib+3];
            #pragma unroll
            for (int nt = 0; nt < 4; ++nt) {
                bf16x8 bfv = *(const bf16x8*)(wt + (nt*16 + o_lane) * (CIN*K2) + k*64 + cb);
                acc[nt] = __builtin_amdgcn_mfma_f32_16x16x32_bf16(af.v, bfv, acc[nt], 0, 0, 0);
            }
        }
        __syncthreads();
    }
    const int o_lane = l & 15, rq = (l >> 4) * 4;
    #pragma unroll
    for (int nt = 0; nt < 4; ++nt) {
        const int o = nt*16 + o_lane;
        #pragma unroll
        for (int j = 0; j < 4; ++j) {
            const int pix = w*16 + rq + j;
            out[(((size_t)b * COUT + o) * HH + ty0 + (pix>>3)) * WW + tx0 + (pix&7)] = acc[nt][j];
        }
    }
}

extern "C" void kernel_launch(void* const* d_in, const int* in_sizes, int n_in,
                              void* d_out, int out_size, void* d_ws, size_t ws_size,
                              hipStream_t stream) {
    const float* x   = (const float*)d_in[0];
    const float* off = (const float*)d_in[1];
    const float* wgt = (const float*)d_in[2];
    float* out = (float*)d_out;

    const size_t xt_bytes = (size_t)8 * HW * 64 * sizeof(unsigned short);     // 16 MiB
    const size_t wt_bytes = (size_t)COUT * CIN * K2 * sizeof(unsigned short); // 72 KiB

    if (ws_size >= xt_bytes + wt_bytes) {
        unsigned short* xt  = (unsigned short*)d_ws;
        unsigned short* wtp = (unsigned short*)((char*)d_ws + xt_bytes);
        xprep2_kernel<<<4096, 256, 0, stream>>>(x, xt);
        wprep_kernel<<<(COUT * CIN * K2 + 255) / 256, 256, 0, stream>>>(wgt, wtp);
        dcn_kernel<<<1024, 1024, 65536, stream>>>(xt, off, wtp, out);
    } else {
        unsigned short* wt = (unsigned short*)d_ws;
        wprep_fb<<<(COUT * CIN * K2 + 255) / 256, 256, 0, stream>>>(wgt, wt);
        dcn_fb<<<2048, 256, 0, stream>>>(x, off, wt, out);
    }
}

// Round 20
// 56.994 us; speedup vs baseline: 1.0600x; 1.0600x over previous
//
#include <hip/hip_runtime.h>
#include <hip/hip_bf16.h>

#define CIN  64
#define HH   128
#define WW   128
#define COUT 64
#define K2   9
#define HW   (HH * WW)

typedef __attribute__((ext_vector_type(8))) short   u16x8;   // raw 16B container
typedef __attribute__((ext_vector_type(8))) _Float16 f16x8;  // MFMA A/B fragment
typedef __attribute__((ext_vector_type(2))) _Float16 f16x2;  // packed-fp16 math
typedef __attribute__((ext_vector_type(4))) float   f32x4;

__device__ __forceinline__ unsigned short f2h(float f) {
    _Float16 h = (_Float16)f;
    return *reinterpret_cast<unsigned short*>(&h);
}
__device__ __forceinline__ unsigned short f2bf(float f) {
    __hip_bfloat16 h = __float2bfloat16(f);
    return *reinterpret_cast<unsigned short*>(&h);
}
__device__ __forceinline__ f16x2 bc(float v) {   // broadcast float -> packed half pair
    _Float16 h = (_Float16)v;
    f16x2 r; r[0] = h; r[1] = h;
    return r;
}
// async global->LDS, 16B per lane; lds dest = wave-uniform base + lane*16
__device__ __forceinline__ void gl2lds16(const unsigned short* g, unsigned short* l) {
    __builtin_amdgcn_global_load_lds(
        (const __attribute__((address_space(1))) unsigned int*)g,
        (__attribute__((address_space(3))) unsigned int*)l, 16, 0, 0);
}

// ---------------- prep: x fp32 NCHW -> fp16 slice-planes [b][s][y][x][8ch] ----------------
__launch_bounds__(256)
__global__ void xprep2_kernel(const float* __restrict__ x, unsigned short* __restrict__ xt) {
    const int idx = blockIdx.x * 256 + threadIdx.x;   // 2^20 total
    const int xw = idx & 127;
    const int y  = (idx >> 7) & 127;
    const int s  = (idx >> 14) & 7;
    const int b  = idx >> 17;
    const float* src = x + (((size_t)(b * CIN + s * 8) * HH) + y) * WW + xw;
    union { unsigned short us[8]; u16x8 v; } u;
    #pragma unroll
    for (int j = 0; j < 8; ++j) u.us[j] = f2h(src[(size_t)j * HW]);
    *(u16x8*)(xt + ((((size_t)b * 8 + s) * HW) + y * WW + xw) * 8) = u.v;
}

// ---------------- prep: weight fp32 [o][c][k] -> fp16 MFMA-B-fragment order ----------------
// wtp[ ((k*2+ks)*4+nt)*512 + l*8 + j ] = W[o=nt*16+(l&15)][c=ks*32+(l>>4)*8+j][k]
__global__ void wprep_kernel(const float* __restrict__ w, unsigned short* __restrict__ wtp) {
    int idx = blockIdx.x * 256 + threadIdx.x;
    if (idx >= COUT * CIN * K2) return;
    int j  = idx & 7;
    int l  = (idx >> 3) & 63;
    int nt = (idx >> 9) & 3;
    int ks = (idx >> 11) & 1;
    int k  = idx >> 12;
    int o  = nt * 16 + (l & 15);
    int c  = ks * 32 + (l >> 4) * 8 + j;
    wtp[idx] = f2h(w[(o * CIN + c) * K2 + k]);
}

// --- main: R13 geometry (K-split 8 waves, all-B in LDS, barrier-free), fp16 data path ---
__launch_bounds__(512, 4)
__global__ void dcn_kernel(const unsigned short* __restrict__ xt,
                           const float* __restrict__ off,
                           const unsigned short* __restrict__ wtp,
                           float* __restrict__ out) {
    extern __shared__ unsigned short lsB[];     // 73728 B: all 9 taps of B (fragment order);
                                                // after tap loop, first 16.9 KB reused as sred
    const int tid = threadIdx.x;
    const int w   = tid >> 6;                   // wave 0..7
    const int l   = tid & 63;
    const int wr  = w & 3;                      // pixel row within tile
    const int wh  = w >> 2;                     // K half: channels wh*32 .. wh*32+31

    int bid = blockIdx.x;
    bid = (bid & 7) * 256 + (bid >> 3);         // XCD swizzle: one batch per XCD
    const int b   = bid >> 8;
    const int t   = bid & 255;
    const int ty0 = (t >> 3) << 2;              // 32 y-tiles of 4
    const int tx0 = (t & 7) << 4;               // 8  x-tiles of 16

    const int g      = l >> 4;                  // k-slice quad within half
    const int lane16 = l & 15;                  // pixel x within row

    // -------- stage ALL B taps into LDS once: 72 segments = 9 rounds x 8 waves --------
    #pragma unroll
    for (int r = 0; r < 9; ++r) {
        const int seg = r * 8 + w;
        gl2lds16(wtp + seg * 512 + l * 8, lsB + seg * 512);
    }

    f32x4 acc[4] = {{0,0,0,0},{0,0,0,0},{0,0,0,0},{0,0,0,0}};

    const float* offb = off + (size_t)b * (2 * K2) * HW;
    // this wave's channel plane: channels (wh*4+g)*8 .. +8
    const unsigned short* xp = xt + ((size_t)b * 8 + (wh * 4 + g)) * HW * 8;

    // this lane's pixel
    const int ypA  = ty0 + wr;
    const int xpA  = tx0 + lane16;
    const int offp = ypA * WW + xpA;

    // ---- pipeline state: constant-indexed after full unroll (spill-safe) ----
    f16x2 Pw[2][4];                             // packed bilinear weights (4 dwords/slot)
    int   Pr0[2], Pr1[2];
    float oyv[2], oxv[2];
    u16x8 Gst[2][4];                            // double-buffered gather stage (1 plane pair)
    f16x8 bvv[4];
    f16x8 af;

#define PARAMS(K, S) do {                                                     \
    const int kdy = (K) / 3 - 1, kdx = (K) % 3 - 1;                           \
    float py = oyv[S] + (float)(ypA + kdy);                                   \
    float px = oxv[S] + (float)(xpA + kdx);                                   \
    float fy = floorf(py), fx = floorf(px);                                   \
    float wy = py - fy, wxn = px - fx;                                        \
    int y0 = (int)fy, x0i = (int)fx;                                          \
    int yc0 = min(max(y0,     0), HH - 1);                                    \
    int yc1 = min(max(y0 + 1, 0), HH - 1);                                    \
    float ay0 = (y0 >= 0  && y0 <= HH - 1) ? (1.f - wy) : 0.f;                \
    float ay1 = (y0 >= -1 && y0 <= HH - 2) ? wy         : 0.f;                \
    int   xL  = min(max(x0i, 0), WW - 2);                                     \
    float bx0 = (x0i >= 0  && x0i <= WW - 1) ? (1.f - wxn) : 0.f;             \
    float bx1 = (x0i >= -1 && x0i <= WW - 2) ? wxn         : 0.f;             \
    bool  sw  = (x0i != xL);                                                  \
    float wxa = sw ? bx1 : bx0;                                               \
    float wxb = sw ? bx0 : bx1;                                               \
    Pw[S][0] = bc(ay0 * wxa); Pw[S][1] = bc(ay0 * wxb);                       \
    Pw[S][2] = bc(ay1 * wxa); Pw[S][3] = bc(ay1 * wxb);                       \
    Pr0[S] = (yc0 * WW + xL) * 8;                                             \
    Pr1[S] = (yc1 * WW + xL) * 8;                                             \
} while (0)

#define GATHER(S) do {                                                        \
    const unsigned short* r0p = xp + Pr0[S];                                  \
    const unsigned short* r1p = xp + Pr1[S];                                  \
    Gst[S][0] = *(const u16x8*)(r0p); Gst[S][1] = *(const u16x8*)(r0p + 8);   \
    Gst[S][2] = *(const u16x8*)(r1p); Gst[S][3] = *(const u16x8*)(r1p + 8);   \
} while (0)

// packed-fp16 bilinear: 4 x v_pk_fma_f16 per dword pair, no unpack, no convert-out
#define INTERP(S) do {                                                        \
    union { u16x8 v; f16x2 h[4]; } ua, ub, uc, ud;                            \
    ua.v = Gst[S][0]; ub.v = Gst[S][1]; uc.v = Gst[S][2]; ud.v = Gst[S][3];   \
    union { f16x2 h[4]; f16x8 v; } rr;                                        \
    _Pragma("unroll")                                                         \
    for (int q = 0; q < 4; ++q) {                                             \
        rr.h[q] = ua.h[q] * Pw[S][0] + ub.h[q] * Pw[S][1]                     \
                + uc.h[q] * Pw[S][2] + ud.h[q] * Pw[S][3];                    \
    }                                                                         \
    af = rr.v;                                                                \
} while (0)

#define BVLOAD(K) do {                                                        \
    _Pragma("unroll")                                                         \
    for (int nt = 0; nt < 4; ++nt)                                            \
        bvv[nt] = *(const f16x8*)(&lsB[(((K) * 2 + wh) * 4 + nt) * 512 + l * 8]); \
} while (0)

#define DOMFMA() do {                                                         \
    __builtin_amdgcn_s_setprio(1);                                            \
    acc[0] = __builtin_amdgcn_mfma_f32_16x16x32_f16(af, bvv[0], acc[0], 0, 0, 0); \
    acc[1] = __builtin_amdgcn_mfma_f32_16x16x32_f16(af, bvv[1], acc[1], 0, 0, 0); \
    acc[2] = __builtin_amdgcn_mfma_f32_16x16x32_f16(af, bvv[2], acc[2], 0, 0, 0); \
    acc[3] = __builtin_amdgcn_mfma_f32_16x16x32_f16(af, bvv[3], acc[3], 0, 0, 0); \
    __builtin_amdgcn_s_setprio(0);                                            \
} while (0)

    // -------- prologue: offsets taps 0/1, params 0, gather tap 0 --------
    oyv[0] = offb[offp];          oxv[0] = offb[HW + offp];
    oyv[1] = offb[2 * HW + offp]; oxv[1] = offb[3 * HW + offp];
    PARAMS(0, 0);
    GATHER(0);
    __syncthreads();                            // the ONLY pre-merge barrier: B fully staged

    // -------- 9 tap-steps, fully unrolled, NO barriers (B read-only, gathers in regs) -----
    #pragma unroll
    for (int s = 0; s < K2; ++s) {
        const int cur = s & 1, nxt = cur ^ 1;
        if (s < 8) {
            PARAMS(s + 1, nxt);
            if (s < 7) {
                oyv[cur] = offb[(2 * (s + 2)    ) * HW + offp];
                oxv[cur] = offb[(2 * (s + 2) + 1) * HW + offp];
            }
            GATHER(nxt);                        // in flight across BVLOAD+INTERP+MFMA(s)
        }
        BVLOAD(s);
        INTERP(cur);
        DOMFMA();
    }

#undef PARAMS
#undef GATHER
#undef INTERP
#undef BVLOAD
#undef DOMFMA

    // -------- merge K-halves + store (sred aliases lsB; B is dead now) --------
    float (*sred)[66] = (float (*)[66])lsB;     // 64 x 66 f32 = 16896 B
    __syncthreads();                            // all BVLOADs done before alias write
    // C/D layout: col = l&15 (=o within nt), row = (l>>4)*4+j (= pixel x = g*4+j)
    const int rq = g * 4;
    if (wh == 0) {
        #pragma unroll
        for (int nt = 0; nt < 4; ++nt)
            #pragma unroll
            for (int j = 0; j < 4; ++j)
                sred[wr * 16 + rq + j][nt * 16 + lane16] = acc[nt][j];
    }
    __syncthreads();
    if (wh == 1) {
        #pragma unroll
        for (int nt = 0; nt < 4; ++nt) {
            f32x4 v;
            #pragma unroll
            for (int j = 0; j < 4; ++j)
                v[j] = sred[wr * 16 + rq + j][nt * 16 + lane16] + acc[nt][j];
            const int o  = nt * 16 + lane16;
            const int yy = ty0 + wr;
            const int xx = tx0 + rq;
            *(f32x4*)&out[(((size_t)b * COUT + o) * HH + yy) * WW + xx] = v;
        }
    }
}

// ---------------- fallback path (no xt room): R0 kernel (bf16, unchanged) ----------------
typedef __attribute__((ext_vector_type(8))) short bf16x8;

__global__ void wprep_fb(const float* __restrict__ w, unsigned short* __restrict__ wt) {
    int idx = blockIdx.x * 256 + threadIdx.x;
    if (idx >= COUT * CIN * K2) return;
    int o = idx / (CIN * K2);
    int r = idx % (CIN * K2);
    int k = r / CIN;
    int c = r % CIN;
    wt[idx] = f2bf(w[o * (CIN * K2) + c * K2 + k]);
}

__launch_bounds__(256)
__global__ void dcn_fb(const float* __restrict__ x, const float* __restrict__ off,
                       const unsigned short* __restrict__ wt, float* __restrict__ out) {
    __shared__ unsigned short s_s[64 * 66];
    const int tid = threadIdx.x;
    const int w = tid >> 6, l = tid & 63;
    const int bid = blockIdx.x;
    const int b = bid >> 8, t = bid & 255;
    const int ty0 = (t >> 4) << 3, tx0 = (t & 15) << 3;
    const int iy = l >> 3, ix = l & 7;
    const int ypix = ty0 + iy, xpix = tx0 + ix;
    f32x4 acc[4] = {{0,0,0,0},{0,0,0,0},{0,0,0,0},{0,0,0,0}};
    const int c0w = w * 16;
    for (int k = 0; k < K2; ++k) {
        float dy = off[(((b * (2*K2)) + 2*k    ) * HH + ypix) * WW + xpix];
        float dx = off[(((b * (2*K2)) + 2*k + 1) * HH + ypix) * WW + xpix];
        float py = dy + (float)(k / 3 + ypix - 1);
        float px = dx + (float)(k % 3 + xpix - 1);
        float fy = floorf(py), fx = floorf(px);
        float wy = py - fy, wx = px - fx;
        int y0 = (int)fy, x0 = (int)fx;
        int yc0 = min(max(y0, 0), HH-1), yc1 = min(max(y0+1, 0), HH-1);
        float ay0 = (y0 >= 0 && y0 <= HH-1) ? (1.f-wy) : 0.f;
        float ay1 = (y0 >= -1 && y0 <= HH-2) ? wy : 0.f;
        int xL = min(max(x0, 0), WW-2);
        float bx0 = (x0 >= 0 && x0 <= WW-1) ? (1.f-wx) : 0.f;
        float bx1 = (x0 >= -1 && x0 <= WW-2) ? wx : 0.f;
        bool sw = (x0 != xL);
        float wxa = sw ? bx1 : bx0, wxb = sw ? bx0 : bx1;
        float W0x = ay0*wxa, W0y = ay0*wxb, W1x = ay1*wxa, W1y = ay1*wxb;
        const float* r0 = x + ((b * CIN + c0w) * HH + yc0) * WW + xL;
        const float* r1 = x + ((b * CIN + c0w) * HH + yc1) * WW + xL;
        unsigned short* sd = &s_s[l * 66 + c0w];
        #pragma unroll
        for (int cc = 0; cc < 16; ++cc) {
            sd[cc] = f2bf(W0x*r0[0] + W0y*r0[1] + W1x*r1[0] + W1y*r1[1]);
            r0 += HH*WW; r1 += HH*WW;
        }
        __syncthreads();
        const int o_lane = l & 15, q = l >> 4;
        #pragma unroll
        for (int ks = 0; ks < 2; ++ks) {
            const int cb = ks*32 + q*8;
            const int row = w*16 + o_lane;
            const unsigned int* sp = (const unsigned int*)s_s;
            const int ib = row*33 + (cb >> 1);
            union { unsigned int u[4]; bf16x8 v; } af;
            af.u[0]=sp[ib]; af.u[1]=sp[ib+1]; af.u[2]=sp[ib+2]; af.u[3]=sp[ib+3];
            #pragma unroll
            for (int nt = 0; nt < 4; ++nt) {
                bf16x8 bfv = *(const bf16x8*)(wt + (nt*16 + o_lane) * (CIN*K2) + k*64 + cb);
                acc[nt] = __builtin_amdgcn_mfma_f32_16x16x32_bf16(af.v, bfv, acc[nt], 0, 0, 0);
            }
        }
        __syncthreads();
    }
    const int o_lane = l & 15, rq = (l >> 4) * 4;
    #pragma unroll
    for (int nt = 0; nt < 4; ++nt) {
        const int o = nt*16 + o_lane;
        #pragma unroll
        for (int j = 0; j < 4; ++j) {
            const int pix = w*16 + rq + j;
            out[(((size_t)b * COUT + o) * HH + ty0 + (pix>>3)) * WW + tx0 + (pix&7)] = acc[nt][j];
        }
    }
}

extern "C" void kernel_launch(void* const* d_in, const int* in_sizes, int n_in,
                              void* d_out, int out_size, void* d_ws, size_t ws_size,
                              hipStream_t stream) {
    const float* x   = (const float*)d_in[0];
    const float* off = (const float*)d_in[1];
    const float* wgt = (const float*)d_in[2];
    float* out = (float*)d_out;

    const size_t xt_bytes = (size_t)8 * HW * 64 * sizeof(unsigned short);     // 16 MiB
    const size_t wt_bytes = (size_t)COUT * CIN * K2 * sizeof(unsigned short); // 72 KiB

    if (ws_size >= xt_bytes + wt_bytes) {
        unsigned short* xt  = (unsigned short*)d_ws;
        unsigned short* wtp = (unsigned short*)((char*)d_ws + xt_bytes);
        xprep2_kernel<<<4096, 256, 0, stream>>>(x, xt);
        wprep_kernel<<<(COUT * CIN * K2 + 255) / 256, 256, 0, stream>>>(wgt, wtp);
        dcn_kernel<<<2048, 512, 73728, stream>>>(xt, off, wtp, out);
    } else {
        unsigned short* wt = (unsigned short*)d_ws;
        wprep_fb<<<(COUT * CIN * K2 + 255) / 256, 256, 0, stream>>>(wgt, wt);
        dcn_fb<<<2048, 256, 0, stream>>>(x, off, wt, out);
    }
}